// Round 12
// baseline (123.922 us; speedup 1.0000x reference)
//
#include <hip/hip_runtime.h>

typedef _Float16 f16x8 __attribute__((ext_vector_type(8)));
typedef float    f32x4 __attribute__((ext_vector_type(4)));

#define N_ROWS 8192
#define DIM 64
#define EPS 1e-8f
#define LOG2E 1.4426950408889634f
#define SHIFT 64.0f                      // exp terms scaled by 2^64
#define SHIFT_LN 44.361419555836499802f  // 64 * ln(2)
#define TILE_I 256                       // i-panel (4 waves x 64 rows, mt=4)
#define NBI (N_ROWS / TILE_I)            // 32 panels
#define TB 512                           // EXACTLY one block per CU slot
#define MAXC 17                          // max j-chunks (16 rows each) per block

// ws: top[8192] | bot[8192] | sq[8192] (f32) | xh[8192*64] | xl[8192*64] (f16)

// fused: zero top/bot/out + f16 split + row norms. one wave per row.
__global__ void snn_prep(const float* __restrict__ x, _Float16* __restrict__ xh,
                         _Float16* __restrict__ xl, float* __restrict__ sq,
                         float* __restrict__ top, float* __restrict__ bot,
                         float* __restrict__ out) {
    const int gt = blockIdx.x * 256 + threadIdx.x;
    if (gt < N_ROWS) { top[gt] = 0.0f; bot[gt] = 0.0f; }
    if (gt == 0) out[0] = 0.0f;
    const int row = gt >> 6, lane = threadIdx.x & 63;
    float v = x[row * DIM + lane];
    _Float16 h = (_Float16)v;
    _Float16 l = (_Float16)(v - (float)h);
    xh[row * DIM + lane] = h;
    xl[row * DIM + lane] = l;
    float s = v * v;
    #pragma unroll
    for (int off = 32; off > 0; off >>= 1) s += __shfl_xor(s, off, 64);
    if (lane == 0) sq[row] = s;
}

// Symmetric triangular pass, R8 partition (512 uniform blocks, ONE scheduling
// round), mt=4 body, evolved per the R11 stall model
// (chunk-slot wall ~2900cyc = issue ~1870 + shuffle-chain ~250 + B-miss ~900;
//  a=0.37us/segment, b=2.07us/chunk from the R8/R11 two-point fit):
//  - col-side kq-reduce shuffles ELIMINATED: each lane stores its jt/jb
//    partial to s_jt[wv][kq][col] (64 distinct addrs, <=2-way bank alias =
//    free); the reduction moves to the one-time drain. -250cyc dep chain +
//    -4 VALU per chunk.
//  - FOUR j-chunks per iteration (segments 9 -> 5): each segment pays one
//    un-hideable B-tile miss (all 4 waves load the SAME tile -> intra-block
//    TLP can't hide it; that's also why R10's 4 waves/SIMD was null).
//    Live B-state 4x16=64 regs, total ~220 < 256 cap: deterministic, not
//    the R3 unbounded-hoist trap.
__global__ __launch_bounds__(256, 2) void snn_mfma(
    const _Float16* __restrict__ xh, const _Float16* __restrict__ xl,
    const float* __restrict__ sq, const int* __restrict__ y,
    const float* __restrict__ w,
    float* __restrict__ top, float* __restrict__ bot)
{
    __shared__ float s_sqj[MAXC * 16];
    __shared__ int   s_yj[MAXC * 16];
    __shared__ float s_jt[4][4][MAXC * 16];  // [wave][kq][col] col-side top
    __shared__ float s_jb[4][4][MAXC * 16];  // [wave][kq][col] col-side bot

    // ---- decode bid -> (panel bi, chunk range [c0, c0+len)) — R8 verbatim ----
    const int bid = blockIdx.x;
    int bi = 0, kk = 0, cum = 0;
    for (int p = 0; p < NBI; p++) {
        int nb = (p < 16) ? p + 1 : p;          // blocks in panel p
        if (bid < cum + nb) { bi = p; kk = bid - cum; break; }
        cum += nb;
    }
    int c0, len;
    if (bi < 16)      { c0 = 16 * kk;              len = 16; }
    else if (kk < 16) { c0 = 17 * kk;              len = 17; }
    else              { c0 = 272 + 16 * (kk - 16); len = 16; }
    const int ndch = min(max(16 * bi - c0, 0), len);  // leading non-diag chunks
    const int I0 = bi * TILE_I;

    const int tid = threadIdx.x, wv = tid >> 6, lane = tid & 63;
    const int mrow = lane & 15, kq = lane >> 4;

    for (int t = tid; t < len * 16; t += 256) {
        s_sqj[t] = sq[c0 * 16 + t];
        s_yj[t]  = y[c0 * 16 + t];
    }
    __syncthreads();

    const int iw = I0 + wv * 64;   // this wave's first i-row

    // A fragments resident for the block lifetime (64 VGPRs)
    f16x8 ah[4][2], al[4][2];
    #pragma unroll
    for (int mt = 0; mt < 4; mt++)
        #pragma unroll
        for (int kc = 0; kc < 2; kc++) {
            int a = (iw + mt * 16 + mrow) * DIM + kc * 32 + kq * 8;
            ah[mt][kc] = *(const f16x8*)(xh + a);
            al[mt][kc] = *(const f16x8*)(xl + a);
        }

    // per-slot row metadata: i = iw + mt*16 + kq*4 + rr ; labels packed 4/VGPR
    float sqi[4][4]; int ypack[4];
    #pragma unroll
    for (int mt = 0; mt < 4; mt++) {
        int yp = 0;
        #pragma unroll
        for (int rr = 0; rr < 4; rr++) {
            int i = iw + mt * 16 + kq * 4 + rr;
            sqi[mt][rr] = sq[i];
            yp |= (y[i] & 255) << (8 * rr);
        }
        ypack[mt] = yp;
    }

    float ts[4][4], bs[4][4];
    #pragma unroll
    for (int mt = 0; mt < 4; mt++)
        #pragma unroll
        for (int rr = 0; rr < 4; rr++) { ts[mt][rr] = 0.0f; bs[mt][rr] = 0.0f; }

    const float c1 = -w[0] * LOG2E;
    f32x4 acc[4];

// declare + issue loads for one chunk (suffix N), chunk index NTL
#define DECL_LOAD(N, NTL)                                                        \
    const int jr##N = (c0 + (NTL)) * 16 + mrow;                                  \
    const int boff##N = jr##N * DIM + kq * 8;                                    \
    f16x8 cbh0##N = *(const f16x8*)(xh + boff##N);                               \
    f16x8 cbh1##N = *(const f16x8*)(xh + boff##N + 32);                          \
    f16x8 cbl0##N = *(const f16x8*)(xl + boff##N);                               \
    f16x8 cbl1##N = *(const f16x8*)(xl + boff##N + 32);                          \
    const float sqj##N = s_sqj[(NTL) * 16 + mrow];                               \
    const int   yj##N  = s_yj[(NTL) * 16 + mrow];

#define DO_MFMA(N)                                                               \
    _Pragma("unroll")                                                            \
    for (int mt = 0; mt < 4; mt++) acc[mt] = (f32x4){0.f, 0.f, 0.f, 0.f};        \
    _Pragma("unroll")                                                            \
    for (int mt = 0; mt < 4; mt++)                                               \
        acc[mt] = __builtin_amdgcn_mfma_f32_16x16x32_f16(ah[mt][0], cbh0##N, acc[mt], 0, 0, 0); \
    _Pragma("unroll")                                                            \
    for (int mt = 0; mt < 4; mt++)                                               \
        acc[mt] = __builtin_amdgcn_mfma_f32_16x16x32_f16(ah[mt][1], cbh1##N, acc[mt], 0, 0, 0); \
    _Pragma("unroll")                                                            \
    for (int mt = 0; mt < 4; mt++)                                               \
        acc[mt] = __builtin_amdgcn_mfma_f32_16x16x32_f16(ah[mt][0], cbl0##N, acc[mt], 0, 0, 0); \
    _Pragma("unroll")                                                            \
    for (int mt = 0; mt < 4; mt++)                                               \
        acc[mt] = __builtin_amdgcn_mfma_f32_16x16x32_f16(ah[mt][1], cbl1##N, acc[mt], 0, 0, 0); \
    _Pragma("unroll")                                                            \
    for (int mt = 0; mt < 4; mt++)                                               \
        acc[mt] = __builtin_amdgcn_mfma_f32_16x16x32_f16(al[mt][0], cbh0##N, acc[mt], 0, 0, 0); \
    _Pragma("unroll")                                                            \
    for (int mt = 0; mt < 4; mt++)                                               \
        acc[mt] = __builtin_amdgcn_mfma_f32_16x16x32_f16(al[mt][1], cbh1##N, acc[mt], 0, 0, 0);

#define EPI_BOTH(N, NTL)                                                         \
    {                                                                            \
        float jt = 0.0f, jb = 0.0f;                                              \
        _Pragma("unroll")                                                        \
        for (int mt = 0; mt < 4; mt++)                                           \
            _Pragma("unroll")                                                    \
            for (int rr = 0; rr < 4; rr++) {                                     \
                float d2 = fmaf(-2.0f, acc[mt][rr], sqi[mt][rr] + sqj##N);       \
                d2 = fmaxf(d2, 0.0f);                                            \
                float dist = __builtin_amdgcn_sqrtf(d2);                         \
                float e2 = __builtin_amdgcn_exp2f(fmaf(c1, dist, SHIFT));        \
                float e2t = (yj##N == ((ypack[mt] >> (8 * rr)) & 255)) ? e2 : 0.0f; \
                ts[mt][rr] += e2t;                                               \
                bs[mt][rr] += e2;                                                \
                jt += e2t;                                                       \
                jb += e2;                                                        \
            }                                                                    \
        s_jt[wv][kq][(NTL) * 16 + mrow] = jt;   /* 64 distinct addrs, no dep */  \
        s_jb[wv][kq][(NTL) * 16 + mrow] = jb;                                    \
    }

#define EPI_DIAG(N, NTL)                                                         \
    {                                                                            \
        _Pragma("unroll")                                                        \
        for (int mt = 0; mt < 4; mt++)                                           \
            _Pragma("unroll")                                                    \
            for (int rr = 0; rr < 4; rr++) {                                     \
                int i = iw + mt * 16 + kq * 4 + rr;                              \
                float d2 = fmaf(-2.0f, acc[mt][rr], sqi[mt][rr] + sqj##N);       \
                d2 = fmaxf(d2, 0.0f);                                            \
                float dist = __builtin_amdgcn_sqrtf(d2);                         \
                float e2 = __builtin_amdgcn_exp2f(fmaf(c1, dist, SHIFT));        \
                bool offd = (i != jr##N);                                        \
                bool same = offd && (yj##N == ((ypack[mt] >> (8 * rr)) & 255));  \
                bs[mt][rr] += offd ? e2 : 0.0f;                                  \
                ts[mt][rr] += same ? e2 : 0.0f;                                  \
            }                                                                    \
    }

    int ntl = 0;
    // ---- both-sided chunks: 4-wide, then 2-wide, then 1-wide remainder ----
    for (; ntl + 4 <= ndch; ntl += 4) {
        DECL_LOAD(0, ntl)
        DECL_LOAD(1, ntl + 1)
        DECL_LOAD(2, ntl + 2)
        DECL_LOAD(3, ntl + 3)
        DO_MFMA(0) EPI_BOTH(0, ntl)
        DO_MFMA(1) EPI_BOTH(1, ntl + 1)
        DO_MFMA(2) EPI_BOTH(2, ntl + 2)
        DO_MFMA(3) EPI_BOTH(3, ntl + 3)
    }
    for (; ntl + 2 <= ndch; ntl += 2) {
        DECL_LOAD(0, ntl)
        DECL_LOAD(1, ntl + 1)
        DO_MFMA(0) EPI_BOTH(0, ntl)
        DO_MFMA(1) EPI_BOTH(1, ntl + 1)
    }
    for (; ntl < ndch; ntl++) {
        DECL_LOAD(0, ntl)
        DO_MFMA(0) EPI_BOTH(0, ntl)
    }
    // ---- diagonal chunks: 4-wide, then 2-wide, then 1-wide remainder ----
    for (; ntl + 4 <= len; ntl += 4) {
        DECL_LOAD(0, ntl)
        DECL_LOAD(1, ntl + 1)
        DECL_LOAD(2, ntl + 2)
        DECL_LOAD(3, ntl + 3)
        DO_MFMA(0) EPI_DIAG(0, ntl)
        DO_MFMA(1) EPI_DIAG(1, ntl + 1)
        DO_MFMA(2) EPI_DIAG(2, ntl + 2)
        DO_MFMA(3) EPI_DIAG(3, ntl + 3)
    }
    for (; ntl + 2 <= len; ntl += 2) {
        DECL_LOAD(0, ntl)
        DECL_LOAD(1, ntl + 1)
        DO_MFMA(0) EPI_DIAG(0, ntl)
        DO_MFMA(1) EPI_DIAG(1, ntl + 1)
    }
    for (; ntl < len; ntl++) {
        DECL_LOAD(0, ntl)
        DO_MFMA(0) EPI_DIAG(0, ntl)
    }
#undef DECL_LOAD
#undef DO_MFMA
#undef EPI_BOTH
#undef EPI_DIAG

    // row-side: reduce across the 16 mrow lanes sharing each row, one atomic/row
    #pragma unroll
    for (int mt = 0; mt < 4; mt++)
        #pragma unroll
        for (int rr = 0; rr < 4; rr++) {
            float tv = ts[mt][rr], bv = bs[mt][rr];
            #pragma unroll
            for (int off = 1; off < 16; off <<= 1) {
                tv += __shfl_xor(tv, off, 64);
                bv += __shfl_xor(bv, off, 64);
            }
            if (mrow == 0) {
                int i = iw + mt * 16 + kq * 4 + rr;
                atomicAdd(&top[i], tv);
                atomicAdd(&bot[i], bv);
            }
        }

    // col-side drain: reduce the 16 (wave,kq) slices, one atomic per column
    if (ndch > 0) {
        __syncthreads();
        for (int t = tid; t < ndch * 16; t += 256) {
            float tt = 0.0f, bb = 0.0f;
            #pragma unroll
            for (int v = 0; v < 4; v++)
                #pragma unroll
                for (int q = 0; q < 4; q++) {
                    tt += s_jt[v][q][t];
                    bb += s_jb[v][q][t];
                }
            atomicAdd(&top[c0 * 16 + t], tt);
            atomicAdd(&bot[c0 * 16 + t], bb);
        }
    }
}

__global__ __launch_bounds__(256) void snn_final(
    const float* __restrict__ top, const float* __restrict__ bot,
    float* __restrict__ out)
{
    const int i = blockIdx.x * 256 + threadIdx.x;
    float t = top[i];                    // top * 2^64, normal fp32
    float b = bot[i] * 0x1p-64f + EPS;   // bot tiny; +eps dominates
    float acc = (logf(t) - SHIFT_LN) - logf(b);
    #pragma unroll
    for (int off = 32; off > 0; off >>= 1) acc += __shfl_xor(acc, off, 64);
    __shared__ float red[4];
    if ((threadIdx.x & 63) == 0) red[threadIdx.x >> 6] = acc;
    __syncthreads();
    if (threadIdx.x == 0) {
        float s = red[0] + red[1] + red[2] + red[3];
        atomicAdd(out, -s / (float)N_ROWS);
    }
}

extern "C" void kernel_launch(void* const* d_in, const int* in_sizes, int n_in,
                              void* d_out, int out_size, void* d_ws, size_t ws_size,
                              hipStream_t stream) {
    const float* x = (const float*)d_in[0];
    const int*   y = (const int*)d_in[1];
    const float* w = (const float*)d_in[2];
    float* out = (float*)d_out;

    float* ws  = (float*)d_ws;
    float* top = ws;
    float* bot = ws + N_ROWS;
    float* sq  = ws + 2 * N_ROWS;
    _Float16* xh = (_Float16*)(ws + 3 * N_ROWS);
    _Float16* xl = xh + (size_t)N_ROWS * DIM;

    snn_prep<<<N_ROWS / 4, 256, 0, stream>>>(x, xh, xl, sq, top, bot, out);
    snn_mfma<<<TB, 256, 0, stream>>>(xh, xl, sq, y, w, top, bot);
    snn_final<<<N_ROWS / 256, 256, 0, stream>>>(top, bot, out);
}

// Round 13
// 94.264 us; speedup vs baseline: 1.3146x; 1.3146x over previous
//
#include <hip/hip_runtime.h>

typedef _Float16 f16x8 __attribute__((ext_vector_type(8)));
typedef float    f32x4 __attribute__((ext_vector_type(4)));
typedef float    f32x2 __attribute__((ext_vector_type(2)));

#define N_ROWS 8192
#define DIM 64
#define EPS 1e-8f
#define LOG2E 1.4426950408889634f
#define SHIFT 64.0f                      // exp terms scaled by 2^64
#define SHIFT_LN 44.361419555836499802f  // 64 * ln(2)
#define TILE_I 256                       // i-panel (4 waves x 64 rows, mt=4)
#define NBI (N_ROWS / TILE_I)            // 32 panels
#define TB 512                           // EXACTLY one block per CU slot
#define MAXC 17                          // max j-chunks (16 rows each) per block

// ws: top[8192] | bot[8192] | sq[8192] (f32) | xh[8192*64] | xl[8192*64] (f16)

// fused: zero top/bot/out + f16 split + row norms. one wave per row.
__global__ void snn_prep(const float* __restrict__ x, _Float16* __restrict__ xh,
                         _Float16* __restrict__ xl, float* __restrict__ sq,
                         float* __restrict__ top, float* __restrict__ bot,
                         float* __restrict__ out) {
    const int gt = blockIdx.x * 256 + threadIdx.x;
    if (gt < N_ROWS) { top[gt] = 0.0f; bot[gt] = 0.0f; }
    if (gt == 0) out[0] = 0.0f;
    const int row = gt >> 6, lane = threadIdx.x & 63;
    float v = x[row * DIM + lane];
    _Float16 h = (_Float16)v;
    _Float16 l = (_Float16)(v - (float)h);
    xh[row * DIM + lane] = h;
    xl[row * DIM + lane] = l;
    float s = v * v;
    #pragma unroll
    for (int off = 32; off > 0; off >>= 1) s += __shfl_xor(s, off, 64);
    if (lane == 0) sq[row] = s;
}

// Symmetric triangular pass, R8 partition (512 uniform blocks, ONE scheduling
// round), R11's 2-wide mt=4 body (best measured: mfma ~38.5us), plus ONLY the
// register-safe half of R12:
//  - col-side kq-reduce shuffles replaced by one per-lane float2 LDS store
//    to s_j[wv][kq][col] (64 distinct 8B slots, <=2-way alias = free); the
//    16-slice reduction moves to the one-time drain. Removes the 4-deep
//    __shfl_xor dep chain + 4 VALU per chunk, no divergent kq==0 store.
//  - R12 post-mortem: the 128-VGPR wall is empirical law under (256,2)
//    (13 compiles, never >128; >128 live state -> spill: R3/R9/R12). 2-wide
//    (~112 live) is the widest fitting body; 4-wide spilled (WRITE 5->19MB).
__global__ __launch_bounds__(256, 2) void snn_mfma(
    const _Float16* __restrict__ xh, const _Float16* __restrict__ xl,
    const float* __restrict__ sq, const int* __restrict__ y,
    const float* __restrict__ w,
    float* __restrict__ top, float* __restrict__ bot)
{
    __shared__ float s_sqj[MAXC * 16];
    __shared__ int   s_yj[MAXC * 16];
    __shared__ f32x2 s_j[4][4][MAXC * 16];   // [wave][kq][col] {top,bot} partials

    // ---- decode bid -> (panel bi, chunk range [c0, c0+len)) — R8 verbatim ----
    const int bid = blockIdx.x;
    int bi = 0, kk = 0, cum = 0;
    for (int p = 0; p < NBI; p++) {
        int nb = (p < 16) ? p + 1 : p;          // blocks in panel p
        if (bid < cum + nb) { bi = p; kk = bid - cum; break; }
        cum += nb;
    }
    int c0, len;
    if (bi < 16)      { c0 = 16 * kk;              len = 16; }
    else if (kk < 16) { c0 = 17 * kk;              len = 17; }
    else              { c0 = 272 + 16 * (kk - 16); len = 16; }
    const int ndch = min(max(16 * bi - c0, 0), len);  // leading non-diag chunks
    const int I0 = bi * TILE_I;

    const int tid = threadIdx.x, wv = tid >> 6, lane = tid & 63;
    const int mrow = lane & 15, kq = lane >> 4;

    for (int t = tid; t < len * 16; t += 256) {
        s_sqj[t] = sq[c0 * 16 + t];
        s_yj[t]  = y[c0 * 16 + t];
    }
    __syncthreads();

    const int iw = I0 + wv * 64;   // this wave's first i-row

    // A fragments resident for the block lifetime (64 VGPRs)
    f16x8 ah[4][2], al[4][2];
    #pragma unroll
    for (int mt = 0; mt < 4; mt++)
        #pragma unroll
        for (int kc = 0; kc < 2; kc++) {
            int a = (iw + mt * 16 + mrow) * DIM + kc * 32 + kq * 8;
            ah[mt][kc] = *(const f16x8*)(xh + a);
            al[mt][kc] = *(const f16x8*)(xl + a);
        }

    // per-slot row metadata: i = iw + mt*16 + kq*4 + rr ; labels packed 4/VGPR
    float sqi[4][4]; int ypack[4];
    #pragma unroll
    for (int mt = 0; mt < 4; mt++) {
        int yp = 0;
        #pragma unroll
        for (int rr = 0; rr < 4; rr++) {
            int i = iw + mt * 16 + kq * 4 + rr;
            sqi[mt][rr] = sq[i];
            yp |= (y[i] & 255) << (8 * rr);
        }
        ypack[mt] = yp;
    }

    float ts[4][4], bs[4][4];
    #pragma unroll
    for (int mt = 0; mt < 4; mt++)
        #pragma unroll
        for (int rr = 0; rr < 4; rr++) { ts[mt][rr] = 0.0f; bs[mt][rr] = 0.0f; }

    const float c1 = -w[0] * LOG2E;
    f32x4 acc[4];

// declare + issue loads for one chunk (suffix N), chunk index NTL
#define DECL_LOAD(N, NTL)                                                        \
    const int jr##N = (c0 + (NTL)) * 16 + mrow;                                  \
    const int boff##N = jr##N * DIM + kq * 8;                                    \
    f16x8 cbh0##N = *(const f16x8*)(xh + boff##N);                               \
    f16x8 cbh1##N = *(const f16x8*)(xh + boff##N + 32);                          \
    f16x8 cbl0##N = *(const f16x8*)(xl + boff##N);                               \
    f16x8 cbl1##N = *(const f16x8*)(xl + boff##N + 32);                          \
    const float sqj##N = s_sqj[(NTL) * 16 + mrow];                               \
    const int   yj##N  = s_yj[(NTL) * 16 + mrow];

#define DO_MFMA(N)                                                               \
    _Pragma("unroll")                                                            \
    for (int mt = 0; mt < 4; mt++) acc[mt] = (f32x4){0.f, 0.f, 0.f, 0.f};        \
    _Pragma("unroll")                                                            \
    for (int mt = 0; mt < 4; mt++)                                               \
        acc[mt] = __builtin_amdgcn_mfma_f32_16x16x32_f16(ah[mt][0], cbh0##N, acc[mt], 0, 0, 0); \
    _Pragma("unroll")                                                            \
    for (int mt = 0; mt < 4; mt++)                                               \
        acc[mt] = __builtin_amdgcn_mfma_f32_16x16x32_f16(ah[mt][1], cbh1##N, acc[mt], 0, 0, 0); \
    _Pragma("unroll")                                                            \
    for (int mt = 0; mt < 4; mt++)                                               \
        acc[mt] = __builtin_amdgcn_mfma_f32_16x16x32_f16(ah[mt][0], cbl0##N, acc[mt], 0, 0, 0); \
    _Pragma("unroll")                                                            \
    for (int mt = 0; mt < 4; mt++)                                               \
        acc[mt] = __builtin_amdgcn_mfma_f32_16x16x32_f16(ah[mt][1], cbl1##N, acc[mt], 0, 0, 0); \
    _Pragma("unroll")                                                            \
    for (int mt = 0; mt < 4; mt++)                                               \
        acc[mt] = __builtin_amdgcn_mfma_f32_16x16x32_f16(al[mt][0], cbh0##N, acc[mt], 0, 0, 0); \
    _Pragma("unroll")                                                            \
    for (int mt = 0; mt < 4; mt++)                                               \
        acc[mt] = __builtin_amdgcn_mfma_f32_16x16x32_f16(al[mt][1], cbh1##N, acc[mt], 0, 0, 0);

#define EPI_BOTH(N, NTL)                                                         \
    {                                                                            \
        float jt = 0.0f, jb = 0.0f;                                              \
        _Pragma("unroll")                                                        \
        for (int mt = 0; mt < 4; mt++)                                           \
            _Pragma("unroll")                                                    \
            for (int rr = 0; rr < 4; rr++) {                                     \
                float d2 = fmaf(-2.0f, acc[mt][rr], sqi[mt][rr] + sqj##N);       \
                d2 = fmaxf(d2, 0.0f);                                            \
                float dist = __builtin_amdgcn_sqrtf(d2);                         \
                float e2 = __builtin_amdgcn_exp2f(fmaf(c1, dist, SHIFT));        \
                float e2t = (yj##N == ((ypack[mt] >> (8 * rr)) & 255)) ? e2 : 0.0f; \
                ts[mt][rr] += e2t;                                               \
                bs[mt][rr] += e2;                                                \
                jt += e2t;                                                       \
                jb += e2;                                                        \
            }                                                                    \
        s_j[wv][kq][(NTL) * 16 + mrow] = (f32x2){jt, jb};  /* no shuffles */     \
    }

#define EPI_DIAG(N, NTL)                                                         \
    {                                                                            \
        _Pragma("unroll")                                                        \
        for (int mt = 0; mt < 4; mt++)                                           \
            _Pragma("unroll")                                                    \
            for (int rr = 0; rr < 4; rr++) {                                     \
                int i = iw + mt * 16 + kq * 4 + rr;                              \
                float d2 = fmaf(-2.0f, acc[mt][rr], sqi[mt][rr] + sqj##N);       \
                d2 = fmaxf(d2, 0.0f);                                            \
                float dist = __builtin_amdgcn_sqrtf(d2);                         \
                float e2 = __builtin_amdgcn_exp2f(fmaf(c1, dist, SHIFT));        \
                bool offd = (i != jr##N);                                        \
                bool same = offd && (yj##N == ((ypack[mt] >> (8 * rr)) & 255));  \
                bs[mt][rr] += offd ? e2 : 0.0f;                                  \
                ts[mt][rr] += same ? e2 : 0.0f;                                  \
            }                                                                    \
    }

    int ntl = 0;
    // ---- both-sided chunks, 2-wide + remainder ----
    for (; ntl + 2 <= ndch; ntl += 2) {
        DECL_LOAD(0, ntl)
        DECL_LOAD(1, ntl + 1)
        DO_MFMA(0) EPI_BOTH(0, ntl)
        DO_MFMA(1) EPI_BOTH(1, ntl + 1)
    }
    for (; ntl < ndch; ntl++) {
        DECL_LOAD(0, ntl)
        DO_MFMA(0) EPI_BOTH(0, ntl)
    }
    // ---- diagonal chunks, 2-wide + remainder ----
    for (; ntl + 2 <= len; ntl += 2) {
        DECL_LOAD(0, ntl)
        DECL_LOAD(1, ntl + 1)
        DO_MFMA(0) EPI_DIAG(0, ntl)
        DO_MFMA(1) EPI_DIAG(1, ntl + 1)
    }
    for (; ntl < len; ntl++) {
        DECL_LOAD(0, ntl)
        DO_MFMA(0) EPI_DIAG(0, ntl)
    }
#undef DECL_LOAD
#undef DO_MFMA
#undef EPI_BOTH
#undef EPI_DIAG

    // row-side: reduce across the 16 mrow lanes sharing each row, one atomic/row
    #pragma unroll
    for (int mt = 0; mt < 4; mt++)
        #pragma unroll
        for (int rr = 0; rr < 4; rr++) {
            float tv = ts[mt][rr], bv = bs[mt][rr];
            #pragma unroll
            for (int off = 1; off < 16; off <<= 1) {
                tv += __shfl_xor(tv, off, 64);
                bv += __shfl_xor(bv, off, 64);
            }
            if (mrow == 0) {
                int i = iw + mt * 16 + kq * 4 + rr;
                atomicAdd(&top[i], tv);
                atomicAdd(&bot[i], bv);
            }
        }

    // col-side drain: reduce the 16 (wave,kq) float2 slices, one atomic/column
    if (ndch > 0) {
        __syncthreads();
        for (int t = tid; t < ndch * 16; t += 256) {
            float tt = 0.0f, bb = 0.0f;
            #pragma unroll
            for (int v = 0; v < 4; v++)
                #pragma unroll
                for (int q = 0; q < 4; q++) {
                    f32x2 s = s_j[v][q][t];
                    tt += s[0];
                    bb += s[1];
                }
            atomicAdd(&top[c0 * 16 + t], tt);
            atomicAdd(&bot[c0 * 16 + t], bb);
        }
    }
}

__global__ __launch_bounds__(256) void snn_final(
    const float* __restrict__ top, const float* __restrict__ bot,
    float* __restrict__ out)
{
    const int i = blockIdx.x * 256 + threadIdx.x;
    float t = top[i];                    // top * 2^64, normal fp32
    float b = bot[i] * 0x1p-64f + EPS;   // bot tiny; +eps dominates
    float acc = (logf(t) - SHIFT_LN) - logf(b);
    #pragma unroll
    for (int off = 32; off > 0; off >>= 1) acc += __shfl_xor(acc, off, 64);
    __shared__ float red[4];
    if ((threadIdx.x & 63) == 0) red[threadIdx.x >> 6] = acc;
    __syncthreads();
    if (threadIdx.x == 0) {
        float s = red[0] + red[1] + red[2] + red[3];
        atomicAdd(out, -s / (float)N_ROWS);
    }
}

extern "C" void kernel_launch(void* const* d_in, const int* in_sizes, int n_in,
                              void* d_out, int out_size, void* d_ws, size_t ws_size,
                              hipStream_t stream) {
    const float* x = (const float*)d_in[0];
    const int*   y = (const int*)d_in[1];
    const float* w = (const float*)d_in[2];
    float* out = (float*)d_out;

    float* ws  = (float*)d_ws;
    float* top = ws;
    float* bot = ws + N_ROWS;
    float* sq  = ws + 2 * N_ROWS;
    _Float16* xh = (_Float16*)(ws + 3 * N_ROWS);
    _Float16* xl = xh + (size_t)N_ROWS * DIM;

    snn_prep<<<N_ROWS / 4, 256, 0, stream>>>(x, xh, xl, sq, top, bot, out);
    snn_mfma<<<TB, 256, 0, stream>>>(xh, xl, sq, y, w, top, bot);
    snn_final<<<N_ROWS / 256, 256, 0, stream>>>(top, bot, out);
}